// Round 1
// baseline (133.582 us; speedup 1.0000x reference)
//
#include <hip/hip_runtime.h>
#include <math.h>

#define HH 76
#define WW 76
#define HW (HH*WW)          // 5776
#define AA 3
#define CC 80
#define TT 50
#define BS 8
#define NN (BS*AA*HW)       // 138624
#define NT (BS*TT)          // 400

// ANCHORS / STRIDE(=8)
__constant__ float c_aw[9] = {17.75f, 24.0f, 57.375f, 4.5f, 9.5f, 9.0f, 1.5f, 2.375f, 5.0f};
__constant__ float c_ah[9] = {13.75f, 30.375f, 50.125f, 9.375f, 6.875f, 18.25f, 2.0f, 4.5f, 3.5f};

__device__ __forceinline__ float sigf(float x) { return 1.0f / (1.0f + expf(-x)); }

// ---------------- prep: per-target best anchor, lin index, class, bls ----------------
__global__ void yolo_prep(const float* __restrict__ tb, const int* __restrict__ tc,
                          double* acc,
                          float* tgx, float* tgy, float* tgw, float* tgh, float* tbls,
                          int* tlin, int* tcl)
{
    int idx = blockIdx.x * blockDim.x + threadIdx.x;
    if (idx < 3) acc[idx] = 0.0;             // zero the 3 double accumulators
    if (idx >= NT) return;

    float t0 = tb[idx*4 + 0];
    float t1 = tb[idx*4 + 1];
    float t2 = tb[idx*4 + 2];
    float t3 = tb[idx*4 + 3];
    float gx = t0 * (float)WW;
    float gy = t1 * (float)HH;
    float gw = t2 * (float)WW;
    float gh = t3 * (float)HH;

    // argmax over 9 anchors of anchor-IoU (first-max wins, like jnp.argmax)
    int best = 0;
    float bestv = -1.0f;
    float ag = gw * gh;
    #pragma unroll
    for (int n = 0; n < 9; n++) {
        float inter = fminf(gw, c_aw[n]) * fminf(gh, c_ah[n]);
        float uni   = ag + c_aw[n]*c_ah[n] - inter;
        float r = inter / uni;
        if (r > bestv) { bestv = r; best = n; }
    }
    int gi = (int)floorf(gx);
    int gj = (int)floorf(gy);
    bool valid = (best >= 6) && (best < 9) && (gi < WW) && (gj < HH);
    int a = best - 6; a = a < 0 ? 0 : (a > 2 ? 2 : a);
    int b = idx / TT;
    int lin = valid ? (((b*AA + a)*HH + gj)*WW + gi) : -1;

    tgx[idx] = gx; tgy[idx] = gy; tgw[idx] = gw; tgh[idx] = gh;
    tbls[idx] = 2.0f - t2 * t3;
    tlin[idx] = lin;
    tcl[idx]  = tc[idx];
}

// ---------------- main: per-cell conf/ignore/cls/loc, reduce to 3 doubles ----------------
__global__ __launch_bounds__(256) void yolo_main(const float* __restrict__ in,
    const float* __restrict__ tgx, const float* __restrict__ tgy,
    const float* __restrict__ tgw, const float* __restrict__ tgh,
    const float* __restrict__ tbls,
    const int* __restrict__ tlin, const int* __restrict__ tcl,
    double* acc)
{
    __shared__ float sgx[NT], sgy[NT], sgw[NT], sgh[NT], sbls[NT];
    __shared__ int slin[NT], scls[NT];
    __shared__ double sred[3][4];

    for (int k = threadIdx.x; k < NT; k += blockDim.x) {
        sgx[k] = tgx[k]; sgy[k] = tgy[k]; sgw[k] = tgw[k]; sgh[k] = tgh[k];
        sbls[k] = tbls[k]; slin[k] = tlin[k]; scls[k] = tcl[k];
    }
    __syncthreads();

    double accConf = 0.0, accCls = 0.0, accLoc = 0.0;
    int n = blockIdx.x * blockDim.x + threadIdx.x;
    if (n < NN) {
        int i = n % WW;
        int j = (n / WW) % HH;
        int a = (n / HW) % AA;
        int b = n / (AA*HW);

        const float* p = in + (size_t)(b*(AA*(5+CC)) + a*(5+CC))*HW + j*WW + i;
        float tx  = p[0];
        float ty  = p[HW];
        float tw  = p[2*HW];
        float th  = p[3*HW];
        float tcf = p[4*HW];

        float px = sigf(tx) + (float)i;
        float py = sigf(ty) + (float)j;
        float pw = expf(tw) * c_aw[6 + a];
        float ph = expf(th) * c_ah[6 + a];
        float conf = sigf(tcf);

        float p1x = px - 0.5f*pw, p2x = px + 0.5f*pw;
        float p1y = py - 0.5f*ph, p2y = py + 0.5f*ph;
        float areap = pw * ph;

        float ioumax = 0.0f;
        int match = -1;
        int tbase = b * TT;
        for (int t = 0; t < TT; t++) {
            float gx = sgx[tbase+t], gy = sgy[tbase+t];
            float gw = sgw[tbase+t], gh = sgh[tbase+t];
            float iw = fmaxf(fminf(gx + 0.5f*gw, p2x) - fmaxf(gx - 0.5f*gw, p1x), 0.0f);
            float ih = fmaxf(fminf(gy + 0.5f*gh, p2y) - fmaxf(gy - 0.5f*gh, p1y), 0.0f);
            float inter = iw * ih;
            float iou = inter / (gw*gh + areap - inter);
            ioumax = fmaxf(ioumax, iou);
            if (slin[tbase+t] == n) match = tbase + t;   // last-write-wins
        }

        // conf BCE: obj cells use -log(p); non-obj cells with iou_max <= 0.5 use -log(1-p)
        float pcl = fminf(fmaxf(conf, 1e-7f), 1.0f - 1e-7f);
        if (match >= 0) {
            accConf += (double)(-logf(pcl));
        } else if (ioumax <= 0.5f) {
            accConf += (double)(-logf(1.0f - pcl));
        }

        if (match >= 0) {
            // ---- CIoU loc loss ----
            float gx = sgx[match], gy = sgy[match], gw = sgw[match], gh = sgh[match];
            float bls = sbls[match];
            float g1x = gx - 0.5f*gw, g2x = gx + 0.5f*gw;
            float g1y = gy - 0.5f*gh, g2y = gy + 0.5f*gh;
            float iw = fmaxf(fminf(p2x, g2x) - fmaxf(p1x, g1x), 0.0f);
            float ih = fmaxf(fminf(p2y, g2y) - fmaxf(p1y, g1y), 0.0f);
            float inter = iw * ih;
            float uni = areap + gw*gh - inter;
            float iou = inter / fmaxf(uni, 1e-6f);
            float dx = px - gx, dy = py - gy;
            float cd = dx*dx + dy*dy;
            float ewx = fmaxf(fmaxf(p2x, g2x) - fminf(p1x, g1x), 0.0f);
            float ewy = fmaxf(fmaxf(p2y, g2y) - fminf(p1y, g1y), 0.0f);
            float ediag = ewx*ewx + ewy*ewy;
            float ciou = iou - cd / fmaxf(ediag, 1e-6f);
            float da = atanf(pw / fmaxf(ph, 1e-6f)) - atanf(gw / fmaxf(gh, 1e-6f));
            const float PI2INV4 = 4.0f / (float)(M_PI * M_PI);
            float v = PI2INV4 * da * da;
            float alpha = v / fmaxf(1.0f - iou + v, 1e-6f);
            ciou = ciou - alpha * v;
            accLoc += (double)((1.0f - ciou) * bls);

            // ---- class BCE: union of class bits from ALL matching targets (exact
            // replication of jnp scatter-set with duplicate lin, distinct cls) ----
            unsigned b0 = 0, b1 = 0, b2 = 0;
            for (int t = 0; t < TT; t++) {
                if (slin[tbase+t] == n) {
                    int c = scls[tbase+t];
                    if (c < 32) b0 |= 1u << c;
                    else if (c < 64) b1 |= 1u << (c - 32);
                    else b2 |= 1u << (c - 64);
                }
            }
            const float* pc = p + 5*HW;
            for (int c = 0; c < CC; c++) {
                float lg = pc[c*HW];
                float pp = fminf(fmaxf(sigf(lg), 1e-7f), 1.0f - 1e-7f);
                unsigned bit = (c < 32 ? (b0 >> c) : (c < 64 ? (b1 >> (c-32)) : (b2 >> (c-64)))) & 1u;
                float tgt = bit ? 1.0f : 0.0f;
                accCls += (double)(-(tgt * logf(pp) + (1.0f - tgt) * logf(1.0f - pp)));
            }
        }
    }

    // ---- block reduction: wave64 shuffle, then across 4 waves ----
    for (int off = 32; off > 0; off >>= 1) {
        accConf += __shfl_down(accConf, off);
        accCls  += __shfl_down(accCls,  off);
        accLoc  += __shfl_down(accLoc,  off);
    }
    int wid = threadIdx.x >> 6;
    int lane = threadIdx.x & 63;
    if (lane == 0) { sred[0][wid] = accConf; sred[1][wid] = accCls; sred[2][wid] = accLoc; }
    __syncthreads();
    if (threadIdx.x == 0) {
        double c0 = 0, c1 = 0, c2 = 0;
        for (int w = 0; w < 4; w++) { c0 += sred[0][w]; c1 += sred[1][w]; c2 += sred[2][w]; }
        atomicAdd(&acc[0], c0);
        atomicAdd(&acc[1], c1);
        atomicAdd(&acc[2], c2);
    }
}

// ---------------- finalize ----------------
__global__ void yolo_fin(const double* __restrict__ acc, float* __restrict__ out)
{
    if (threadIdx.x == 0 && blockIdx.x == 0) {
        double lconf = acc[0] / (double)BS;
        double lcls  = acc[1] / (double)BS;
        double lloc  = acc[2] / (double)BS;
        out[0] = (float)(lconf + lcls + lloc);
        out[1] = (float)lconf;
        out[2] = (float)lcls;
        out[3] = (float)lloc;
    }
}

extern "C" void kernel_launch(void* const* d_in, const int* in_sizes, int n_in,
                              void* d_out, int out_size, void* d_ws, size_t ws_size,
                              hipStream_t stream) {
    const float* inp = (const float*)d_in[0];          // (8, 255, 76, 76) fp32
    const float* tb  = (const float*)d_in[1];          // (8, 50, 4) fp32
    const int*   tc  = (const int*)d_in[2];            // (8, 50) int32
    float* out = (float*)d_out;                        // 4 fp32 scalars

    char* ws = (char*)d_ws;
    double* acc = (double*)ws;                         // 3 doubles
    float* tgx  = (float*)(ws + 64);
    float* tgy  = tgx + NT;
    float* tgw  = tgy + NT;
    float* tgh  = tgw + NT;
    float* tbls = tgh + NT;
    int*   tlin = (int*)(tbls + NT);
    int*   tcl  = tlin + NT;

    yolo_prep<<<(NT + 255) / 256, 256, 0, stream>>>(tb, tc, acc, tgx, tgy, tgw, tgh, tbls, tlin, tcl);
    yolo_main<<<(NN + 255) / 256, 256, 0, stream>>>(inp, tgx, tgy, tgw, tgh, tbls, tlin, tcl, acc);
    yolo_fin<<<1, 64, 0, stream>>>(acc, out);
}

// Round 2
// 126.807 us; speedup vs baseline: 1.0534x; 1.0534x over previous
//
#include <hip/hip_runtime.h>
#include <math.h>

#define HH 76
#define WW 76
#define HW (HH*WW)          // 5776
#define AA 3
#define CC 80
#define TT 50
#define BS 8
#define NPB (AA*HW)         // cells per image: 17328
#define CHUNKS ((NPB + 255) / 256)   // 68

// ANCHORS / STRIDE(=8)
__constant__ float c_aw[9] = {17.75f, 24.0f, 57.375f, 4.5f, 9.5f, 9.0f, 1.5f, 2.375f, 5.0f};
__constant__ float c_ah[9] = {13.75f, 30.375f, 50.125f, 9.375f, 6.875f, 18.25f, 2.0f, 4.5f, 3.5f};

__device__ __forceinline__ float sigf(float x) { return 1.0f / (1.0f + expf(-x)); }

__global__ void yolo_zero(float* __restrict__ out) {
    if (threadIdx.x < 4) out[threadIdx.x] = 0.0f;
}

// One block = 256 consecutive cells of one image (blockIdx.y = b).
// Targets for that image are computed in-block (fused prep) into LDS float4s.
__global__ __launch_bounds__(256) void yolo_main(const float* __restrict__ in,
                                                 const float* __restrict__ tb,
                                                 const int* __restrict__ tc,
                                                 float* __restrict__ out)
{
    __shared__ float4 sA[TT];   // x1, y1, x2, y2   (gt box corners)
    __shared__ float4 sB[TT];   // area_g, bls, lin(bits), cls(bits)
    __shared__ float4 sC[TT];   // gx, gy, gw, gh   (for CIoU, rare path)
    __shared__ float  sred[3][4];

    const int b = blockIdx.y;
    const int tid = threadIdx.x;

    // ---- fused prep: 50 threads compute this image's targets ----
    if (tid < TT) {
        int t = b * TT + tid;
        float t0 = tb[t*4 + 0];
        float t1 = tb[t*4 + 1];
        float t2 = tb[t*4 + 2];
        float t3 = tb[t*4 + 3];
        float gx = t0 * (float)WW;
        float gy = t1 * (float)HH;
        float gw = t2 * (float)WW;
        float gh = t3 * (float)HH;

        int best = 0;
        float bestv = -1.0f;
        float ag = gw * gh;
        #pragma unroll
        for (int n = 0; n < 9; n++) {
            float inter = fminf(gw, c_aw[n]) * fminf(gh, c_ah[n]);
            float uni   = ag + c_aw[n]*c_ah[n] - inter;
            float r = inter / uni;
            if (r > bestv) { bestv = r; best = n; }
        }
        int gi = (int)floorf(gx);
        int gj = (int)floorf(gy);
        bool valid = (best >= 6) && (best < 9) && (gi < WW) && (gj < HH);
        int a = best - 6; a = a < 0 ? 0 : (a > 2 ? 2 : a);
        int lin = valid ? ((a*HH + gj)*WW + gi) : -1;   // image-local cell index

        sA[tid] = make_float4(gx - 0.5f*gw, gy - 0.5f*gh, gx + 0.5f*gw, gy + 0.5f*gh);
        sB[tid] = make_float4(ag, 2.0f - t2*t3, __int_as_float(lin), __int_as_float(tc[t]));
        sC[tid] = make_float4(gx, gy, gw, gh);
    }
    __syncthreads();

    float accConf = 0.0f, accCls = 0.0f, accLoc = 0.0f;
    const int n = blockIdx.x * 256 + tid;   // image-local cell index
    if (n < NPB) {
        const int hw = n % HW;          // j*WW + i
        const int i  = n % WW;
        const int j  = (n / WW) % HH;
        const int a  = n / HW;

        const float* p = in + ((size_t)b*(AA*(5+CC)) + (size_t)a*(5+CC))*HW + hw;
        float tx  = p[0];
        float ty  = p[HW];
        float tw  = p[2*HW];
        float th  = p[3*HW];
        float tcf = p[4*HW];

        float px = sigf(tx) + (float)i;
        float py = sigf(ty) + (float)j;
        float pw = expf(tw) * c_aw[6 + a];
        float ph = expf(th) * c_ah[6 + a];
        float conf = sigf(tcf);

        float p1x = px - 0.5f*pw, p2x = px + 0.5f*pw;
        float p1y = py - 0.5f*ph, p2y = py + 0.5f*ph;
        float areap = pw * ph;

        // ---- T=50 ignore loop: 2 pipelined ds_read_b128 per iter ----
        float ioumax = 0.0f;
        int match = -1;
        #pragma unroll 10
        for (int t = 0; t < TT; t++) {
            float4 A = sA[t];
            float4 B = sB[t];
            float iw = fmaxf(fminf(A.z, p2x) - fmaxf(A.x, p1x), 0.0f);
            float ih = fmaxf(fminf(A.w, p2y) - fmaxf(A.y, p1y), 0.0f);
            float inter = iw * ih;
            float iou = inter * __builtin_amdgcn_rcpf(B.x + areap - inter);
            ioumax = fmaxf(ioumax, iou);
            if (__float_as_int(B.z) == n) match = t;   // last-write-wins
        }

        float pcl = fminf(fmaxf(conf, 1e-7f), 1.0f - 1e-7f);
        if (match >= 0) {
            accConf = -logf(pcl);
        } else if (ioumax <= 0.5f) {
            accConf = -logf(1.0f - pcl);
        }

        if (match >= 0) {
            // ---- CIoU loc loss (rare path: <= 400 cells total) ----
            float4 G = sC[match];
            float gx = G.x, gy = G.y, gw = G.z, gh = G.w;
            float bls = sB[match].y;
            float g1x = gx - 0.5f*gw, g2x = gx + 0.5f*gw;
            float g1y = gy - 0.5f*gh, g2y = gy + 0.5f*gh;
            float iw = fmaxf(fminf(p2x, g2x) - fmaxf(p1x, g1x), 0.0f);
            float ih = fmaxf(fminf(p2y, g2y) - fmaxf(p1y, g1y), 0.0f);
            float inter = iw * ih;
            float uni = areap + gw*gh - inter;
            float iou = inter / fmaxf(uni, 1e-6f);
            float dx = px - gx, dy = py - gy;
            float cd = dx*dx + dy*dy;
            float ewx = fmaxf(fmaxf(p2x, g2x) - fminf(p1x, g1x), 0.0f);
            float ewy = fmaxf(fmaxf(p2y, g2y) - fminf(p1y, g1y), 0.0f);
            float ediag = ewx*ewx + ewy*ewy;
            float ciou = iou - cd / fmaxf(ediag, 1e-6f);
            float da = atanf(pw / fmaxf(ph, 1e-6f)) - atanf(gw / fmaxf(gh, 1e-6f));
            const float PI2INV4 = 4.0f / (float)(M_PI * M_PI);
            float v = PI2INV4 * da * da;
            float alpha = v / fmaxf(1.0f - iou + v, 1e-6f);
            ciou = ciou - alpha * v;
            accLoc = (1.0f - ciou) * bls;

            // class bit union over all matching targets (scatter-set replication)
            unsigned b0 = 0, b1 = 0, b2 = 0;
            for (int t = 0; t < TT; t++) {
                if (__float_as_int(sB[t].z) == n) {
                    int c = __float_as_int(sB[t].w);
                    if (c < 32) b0 |= 1u << c;
                    else if (c < 64) b1 |= 1u << (c - 32);
                    else b2 |= 1u << (c - 64);
                }
            }
            const float* pc = p + 5*HW;
            #pragma unroll 8
            for (int c = 0; c < CC; c++) {
                float lg = pc[c*HW];
                float pp = fminf(fmaxf(sigf(lg), 1e-7f), 1.0f - 1e-7f);
                unsigned bit = (c < 32 ? (b0 >> c) : (c < 64 ? (b1 >> (c-32)) : (b2 >> (c-64)))) & 1u;
                float tgt = bit ? 1.0f : 0.0f;
                accCls += -(tgt * logf(pp) + (1.0f - tgt) * logf(1.0f - pp));
            }
        }
    }

    // ---- block reduction: wave64 shuffle, then across 4 waves ----
    for (int off = 32; off > 0; off >>= 1) {
        accConf += __shfl_down(accConf, off);
        accCls  += __shfl_down(accCls,  off);
        accLoc  += __shfl_down(accLoc,  off);
    }
    int wid = tid >> 6;
    int lane = tid & 63;
    if (lane == 0) { sred[0][wid] = accConf; sred[1][wid] = accCls; sred[2][wid] = accLoc; }
    __syncthreads();
    if (tid == 0) {
        float c0 = 0.f, c1 = 0.f, c2 = 0.f;
        #pragma unroll
        for (int w = 0; w < 4; w++) { c0 += sred[0][w]; c1 += sred[1][w]; c2 += sred[2][w]; }
        const float inv_bs = 1.0f / (float)BS;
        c0 *= inv_bs; c1 *= inv_bs; c2 *= inv_bs;
        atomicAdd(&out[0], c0 + c1 + c2);
        atomicAdd(&out[1], c0);
        atomicAdd(&out[2], c1);
        atomicAdd(&out[3], c2);
    }
}

extern "C" void kernel_launch(void* const* d_in, const int* in_sizes, int n_in,
                              void* d_out, int out_size, void* d_ws, size_t ws_size,
                              hipStream_t stream) {
    const float* inp = (const float*)d_in[0];          // (8, 255, 76, 76) fp32
    const float* tb  = (const float*)d_in[1];          // (8, 50, 4) fp32
    const int*   tc  = (const int*)d_in[2];            // (8, 50) int32
    float* out = (float*)d_out;                        // 4 fp32 scalars

    yolo_zero<<<1, 64, 0, stream>>>(out);
    yolo_main<<<dim3(CHUNKS, BS), 256, 0, stream>>>(inp, tb, tc, out);
}

// Round 3
// 108.648 us; speedup vs baseline: 1.2295x; 1.1671x over previous
//
#include <hip/hip_runtime.h>
#include <math.h>

#define HH 76
#define WW 76
#define HW (HH*WW)          // 5776
#define AA 3
#define CC 80
#define TT 50
#define BS 8
#define NPB (AA*HW)         // cells per image: 17328
#define CHUNKS ((NPB + 255) / 256)   // 68
#define NBLK (CHUNKS*BS)             // 544 blocks

// ANCHORS / STRIDE(=8)
__constant__ float c_aw[9] = {17.75f, 24.0f, 57.375f, 4.5f, 9.5f, 9.0f, 1.5f, 2.375f, 5.0f};
__constant__ float c_ah[9] = {13.75f, 30.375f, 50.125f, 9.375f, 6.875f, 18.25f, 2.0f, 4.5f, 3.5f};

__device__ __forceinline__ float sigf(float x) { return 1.0f / (1.0f + expf(-x)); }

// One block = 256 consecutive cells of one image (blockIdx.y = b).
// Targets for that image are computed in-block (fused prep) into LDS float4s.
// Block partials go to d_ws (NO atomics — same-line atomic contention was the
// R1/R2 bottleneck: 544 blocks x 4 atomics to one cache line ~= 52 us drain).
__global__ __launch_bounds__(256) void yolo_main(const float* __restrict__ in,
                                                 const float* __restrict__ tb,
                                                 const int* __restrict__ tc,
                                                 float* __restrict__ part)
{
    __shared__ float4 sA[TT];   // x1, y1, x2, y2   (gt box corners)
    __shared__ float4 sB[TT];   // area_g, bls, lin(bits), cls(bits)
    __shared__ float4 sC[TT];   // gx, gy, gw, gh   (for CIoU, rare path)
    __shared__ float  sred[3][4];

    const int b = blockIdx.y;
    const int tid = threadIdx.x;

    // ---- fused prep: 50 threads compute this image's targets ----
    if (tid < TT) {
        int t = b * TT + tid;
        float t0 = tb[t*4 + 0];
        float t1 = tb[t*4 + 1];
        float t2 = tb[t*4 + 2];
        float t3 = tb[t*4 + 3];
        float gx = t0 * (float)WW;
        float gy = t1 * (float)HH;
        float gw = t2 * (float)WW;
        float gh = t3 * (float)HH;

        int best = 0;
        float bestv = -1.0f;
        float ag = gw * gh;
        #pragma unroll
        for (int n = 0; n < 9; n++) {
            float inter = fminf(gw, c_aw[n]) * fminf(gh, c_ah[n]);
            float uni   = ag + c_aw[n]*c_ah[n] - inter;
            float r = inter / uni;
            if (r > bestv) { bestv = r; best = n; }
        }
        int gi = (int)floorf(gx);
        int gj = (int)floorf(gy);
        bool valid = (best >= 6) && (best < 9) && (gi < WW) && (gj < HH);
        int a = best - 6; a = a < 0 ? 0 : (a > 2 ? 2 : a);
        int lin = valid ? ((a*HH + gj)*WW + gi) : -1;   // image-local cell index

        sA[tid] = make_float4(gx - 0.5f*gw, gy - 0.5f*gh, gx + 0.5f*gw, gy + 0.5f*gh);
        sB[tid] = make_float4(ag, 2.0f - t2*t3, __int_as_float(lin), __int_as_float(tc[t]));
        sC[tid] = make_float4(gx, gy, gw, gh);
    }
    __syncthreads();

    float accConf = 0.0f, accCls = 0.0f, accLoc = 0.0f;
    const int n = blockIdx.x * 256 + tid;   // image-local cell index
    if (n < NPB) {
        const int hw = n % HW;          // j*WW + i
        const int i  = n % WW;
        const int j  = (n / WW) % HH;
        const int a  = n / HW;

        const float* p = in + ((size_t)b*(AA*(5+CC)) + (size_t)a*(5+CC))*HW + hw;
        float tx  = p[0];
        float ty  = p[HW];
        float tw  = p[2*HW];
        float th  = p[3*HW];
        float tcf = p[4*HW];

        float px = sigf(tx) + (float)i;
        float py = sigf(ty) + (float)j;
        float pw = expf(tw) * c_aw[6 + a];
        float ph = expf(th) * c_ah[6 + a];
        float conf = sigf(tcf);

        float p1x = px - 0.5f*pw, p2x = px + 0.5f*pw;
        float p1y = py - 0.5f*ph, p2y = py + 0.5f*ph;
        float areap = pw * ph;

        // ---- T=50 ignore loop: 2 pipelined ds_read_b128 per iter ----
        float ioumax = 0.0f;
        int match = -1;
        #pragma unroll 10
        for (int t = 0; t < TT; t++) {
            float4 A = sA[t];
            float4 B = sB[t];
            float iw = fmaxf(fminf(A.z, p2x) - fmaxf(A.x, p1x), 0.0f);
            float ih = fmaxf(fminf(A.w, p2y) - fmaxf(A.y, p1y), 0.0f);
            float inter = iw * ih;
            float iou = inter * __builtin_amdgcn_rcpf(B.x + areap - inter);
            ioumax = fmaxf(ioumax, iou);
            if (__float_as_int(B.z) == n) match = t;   // last-write-wins
        }

        float pcl = fminf(fmaxf(conf, 1e-7f), 1.0f - 1e-7f);
        if (match >= 0) {
            accConf = -logf(pcl);
        } else if (ioumax <= 0.5f) {
            accConf = -logf(1.0f - pcl);
        }

        if (match >= 0) {
            // ---- CIoU loc loss (rare path: <= 400 cells total) ----
            float4 G = sC[match];
            float gx = G.x, gy = G.y, gw = G.z, gh = G.w;
            float bls = sB[match].y;
            float g1x = gx - 0.5f*gw, g2x = gx + 0.5f*gw;
            float g1y = gy - 0.5f*gh, g2y = gy + 0.5f*gh;
            float iw = fmaxf(fminf(p2x, g2x) - fmaxf(p1x, g1x), 0.0f);
            float ih = fmaxf(fminf(p2y, g2y) - fmaxf(p1y, g1y), 0.0f);
            float inter = iw * ih;
            float uni = areap + gw*gh - inter;
            float iou = inter / fmaxf(uni, 1e-6f);
            float dx = px - gx, dy = py - gy;
            float cd = dx*dx + dy*dy;
            float ewx = fmaxf(fmaxf(p2x, g2x) - fminf(p1x, g1x), 0.0f);
            float ewy = fmaxf(fmaxf(p2y, g2y) - fminf(p1y, g1y), 0.0f);
            float ediag = ewx*ewx + ewy*ewy;
            float ciou = iou - cd / fmaxf(ediag, 1e-6f);
            float da = atanf(pw / fmaxf(ph, 1e-6f)) - atanf(gw / fmaxf(gh, 1e-6f));
            const float PI2INV4 = 4.0f / (float)(M_PI * M_PI);
            float v = PI2INV4 * da * da;
            float alpha = v / fmaxf(1.0f - iou + v, 1e-6f);
            ciou = ciou - alpha * v;
            accLoc = (1.0f - ciou) * bls;

            // class bit union over all matching targets (scatter-set replication)
            unsigned b0 = 0, b1 = 0, b2 = 0;
            for (int t = 0; t < TT; t++) {
                if (__float_as_int(sB[t].z) == n) {
                    int c = __float_as_int(sB[t].w);
                    if (c < 32) b0 |= 1u << c;
                    else if (c < 64) b1 |= 1u << (c - 32);
                    else b2 |= 1u << (c - 64);
                }
            }
            const float* pc = p + 5*HW;
            #pragma unroll 8
            for (int c = 0; c < CC; c++) {
                float lg = pc[c*HW];
                float pp = fminf(fmaxf(sigf(lg), 1e-7f), 1.0f - 1e-7f);
                unsigned bit = (c < 32 ? (b0 >> c) : (c < 64 ? (b1 >> (c-32)) : (b2 >> (c-64)))) & 1u;
                float tgt = bit ? 1.0f : 0.0f;
                accCls += -(tgt * logf(pp) + (1.0f - tgt) * logf(1.0f - pp));
            }
        }
    }

    // ---- block reduction: wave64 shuffle, then across 4 waves ----
    for (int off = 32; off > 0; off >>= 1) {
        accConf += __shfl_down(accConf, off);
        accCls  += __shfl_down(accCls,  off);
        accLoc  += __shfl_down(accLoc,  off);
    }
    int wid = tid >> 6;
    int lane = tid & 63;
    if (lane == 0) { sred[0][wid] = accConf; sred[1][wid] = accCls; sred[2][wid] = accLoc; }
    __syncthreads();
    if (tid == 0) {
        float c0 = 0.f, c1 = 0.f, c2 = 0.f;
        #pragma unroll
        for (int w = 0; w < 4; w++) { c0 += sred[0][w]; c1 += sred[1][w]; c2 += sred[2][w]; }
        const int bid = blockIdx.y * CHUNKS + blockIdx.x;
        part[0*NBLK + bid] = c0;    // component-major for coalesced fin reads
        part[1*NBLK + bid] = c1;
        part[2*NBLK + bid] = c2;
    }
}

// ---- final reduce: 544 partials x 3 comps -> 4 outputs, one block ----
__global__ __launch_bounds__(256) void yolo_fin(const float* __restrict__ part,
                                                float* __restrict__ out)
{
    __shared__ float sred[3][4];
    float c0 = 0.f, c1 = 0.f, c2 = 0.f;
    for (int k = threadIdx.x; k < NBLK; k += 256) {
        c0 += part[0*NBLK + k];
        c1 += part[1*NBLK + k];
        c2 += part[2*NBLK + k];
    }
    for (int off = 32; off > 0; off >>= 1) {
        c0 += __shfl_down(c0, off);
        c1 += __shfl_down(c1, off);
        c2 += __shfl_down(c2, off);
    }
    int wid = threadIdx.x >> 6;
    int lane = threadIdx.x & 63;
    if (lane == 0) { sred[0][wid] = c0; sred[1][wid] = c1; sred[2][wid] = c2; }
    __syncthreads();
    if (threadIdx.x == 0) {
        float s0 = 0.f, s1 = 0.f, s2 = 0.f;
        #pragma unroll
        for (int w = 0; w < 4; w++) { s0 += sred[0][w]; s1 += sred[1][w]; s2 += sred[2][w]; }
        const float inv_bs = 1.0f / (float)BS;
        s0 *= inv_bs; s1 *= inv_bs; s2 *= inv_bs;
        out[0] = s0 + s1 + s2;
        out[1] = s0;
        out[2] = s1;
        out[3] = s2;
    }
}

extern "C" void kernel_launch(void* const* d_in, const int* in_sizes, int n_in,
                              void* d_out, int out_size, void* d_ws, size_t ws_size,
                              hipStream_t stream) {
    const float* inp = (const float*)d_in[0];          // (8, 255, 76, 76) fp32
    const float* tb  = (const float*)d_in[1];          // (8, 50, 4) fp32
    const int*   tc  = (const int*)d_in[2];            // (8, 50) int32
    float* out = (float*)d_out;                        // 4 fp32 scalars
    float* part = (float*)d_ws;                        // 3*NBLK floats

    yolo_main<<<dim3(CHUNKS, BS), 256, 0, stream>>>(inp, tb, tc, part);
    yolo_fin<<<1, 256, 0, stream>>>(part, out);
}

// Round 4
// 92.626 us; speedup vs baseline: 1.4422x; 1.1730x over previous
//
#include <hip/hip_runtime.h>
#include <math.h>

#define HH 76
#define WW 76
#define HW (HH*WW)          // 5776
#define AA 3
#define CC 80
#define TT 50
#define BS 8
#define NPB (AA*HW)         // cells per image: 17328
#define CHUNKS ((NPB + 255) / 256)   // 68
#define NBLK (CHUNKS*BS)             // 544 blocks

// ANCHORS / STRIDE(=8)
__constant__ float c_aw[9] = {17.75f, 24.0f, 57.375f, 4.5f, 9.5f, 9.0f, 1.5f, 2.375f, 5.0f};
__constant__ float c_ah[9] = {13.75f, 30.375f, 50.125f, 9.375f, 6.875f, 18.25f, 2.0f, 4.5f, 3.5f};

__device__ __forceinline__ float sigf(float x) { return 1.0f / (1.0f + expf(-x)); }

// One block = 256 consecutive cells of one image (blockIdx.y = b).
// Targets computed in-block into LDS. Rare matched-cell class-BCE is done
// COOPERATIVELY (a whole wave reads the 80 strided class logits in parallel)
// instead of one thread issuing 80 dependent ~500-cycle loads — that serial
// chain was the remaining ~30 us in R3's yolo_main.
__global__ __launch_bounds__(256) void yolo_main(const float* __restrict__ in,
                                                 const float* __restrict__ tb,
                                                 const int* __restrict__ tc,
                                                 float* __restrict__ part)
{
    __shared__ float4 sA[TT];    // x1, y1, x2, y2 (gt corners)      [hot]
    __shared__ float2 sAL[TT];   // area_g, lin(bits)                [hot]
    __shared__ float4 sC[TT];    // gx, gy, gw, gh                   [rare]
    __shared__ float  sBls[TT];  // box loss scale                   [rare]
    __shared__ int    sCl[TT];   // class index                      [rare]
    __shared__ int4   q[256];    // matched-cell queue: n, b0, b1, b2
    __shared__ int    qcnt;
    __shared__ float  sCls;
    __shared__ float  sred[2][4];

    const int b = blockIdx.y;
    const int tid = threadIdx.x;

    if (tid == 0) { qcnt = 0; sCls = 0.0f; }

    // ---- fused prep: 50 threads compute this image's targets ----
    if (tid < TT) {
        int t = b * TT + tid;
        float t0 = tb[t*4 + 0];
        float t1 = tb[t*4 + 1];
        float t2 = tb[t*4 + 2];
        float t3 = tb[t*4 + 3];
        float gx = t0 * (float)WW;
        float gy = t1 * (float)HH;
        float gw = t2 * (float)WW;
        float gh = t3 * (float)HH;

        int best = 0;
        float bestv = -1.0f;
        float ag = gw * gh;
        #pragma unroll
        for (int n = 0; n < 9; n++) {
            float inter = fminf(gw, c_aw[n]) * fminf(gh, c_ah[n]);
            float uni   = ag + c_aw[n]*c_ah[n] - inter;
            float r = inter / uni;
            if (r > bestv) { bestv = r; best = n; }
        }
        int gi = (int)floorf(gx);
        int gj = (int)floorf(gy);
        bool valid = (best >= 6) && (best < 9) && (gi < WW) && (gj < HH);
        int a = best - 6; a = a < 0 ? 0 : (a > 2 ? 2 : a);
        int lin = valid ? ((a*HH + gj)*WW + gi) : -1;   // image-local cell index

        sA[tid]   = make_float4(gx - 0.5f*gw, gy - 0.5f*gh, gx + 0.5f*gw, gy + 0.5f*gh);
        sAL[tid]  = make_float2(ag, __int_as_float(lin));
        sC[tid]   = make_float4(gx, gy, gw, gh);
        sBls[tid] = 2.0f - t2*t3;
        sCl[tid]  = tc[t];
    }
    __syncthreads();

    float accConf = 0.0f, accLoc = 0.0f;
    const int n = blockIdx.x * 256 + tid;   // image-local cell index
    if (n < NPB) {
        const int hw = n % HW;          // j*WW + i
        const int i  = n % WW;
        const int j  = (n / WW) % HH;
        const int a  = n / HW;

        const float* p = in + ((size_t)b*(AA*(5+CC)) + (size_t)a*(5+CC))*HW + hw;
        float tx  = p[0];
        float ty  = p[HW];
        float tw  = p[2*HW];
        float th  = p[3*HW];
        float tcf = p[4*HW];

        float px = sigf(tx) + (float)i;
        float py = sigf(ty) + (float)j;
        float pw = expf(tw) * c_aw[6 + a];
        float ph = expf(th) * c_ah[6 + a];
        float conf = sigf(tcf);

        float p1x = px - 0.5f*pw, p2x = px + 0.5f*pw;
        float p1y = py - 0.5f*ph, p2y = py + 0.5f*ph;
        float areap = pw * ph;

        // ---- T=50 ignore loop: ds_read_b128 + ds_read_b64 per iter ----
        float ioumax = 0.0f;
        int match = -1;
        #pragma unroll 10
        for (int t = 0; t < TT; t++) {
            float4 A = sA[t];
            float2 L = sAL[t];
            float iw = fmaxf(fminf(A.z, p2x) - fmaxf(A.x, p1x), 0.0f);
            float ih = fmaxf(fminf(A.w, p2y) - fmaxf(A.y, p1y), 0.0f);
            float inter = iw * ih;
            float iou = inter * __builtin_amdgcn_rcpf(L.x + areap - inter);
            ioumax = fmaxf(ioumax, iou);
            if (__float_as_int(L.y) == n) match = t;   // last-write-wins
        }

        float pcl = fminf(fmaxf(conf, 1e-7f), 1.0f - 1e-7f);
        if (match >= 0) {
            accConf = -logf(pcl);
        } else if (ioumax <= 0.5f) {
            accConf = -logf(1.0f - pcl);
        }

        if (match >= 0) {
            // ---- CIoU loc loss (pure VALU, keep per-thread) ----
            float4 G = sC[match];
            float gx = G.x, gy = G.y, gw = G.z, gh = G.w;
            float bls = sBls[match];
            float g1x = gx - 0.5f*gw, g2x = gx + 0.5f*gw;
            float g1y = gy - 0.5f*gh, g2y = gy + 0.5f*gh;
            float iw = fmaxf(fminf(p2x, g2x) - fmaxf(p1x, g1x), 0.0f);
            float ih = fmaxf(fminf(p2y, g2y) - fmaxf(p1y, g1y), 0.0f);
            float inter = iw * ih;
            float uni = areap + gw*gh - inter;
            float iou = inter / fmaxf(uni, 1e-6f);
            float dx = px - gx, dy = py - gy;
            float cd = dx*dx + dy*dy;
            float ewx = fmaxf(fmaxf(p2x, g2x) - fminf(p1x, g1x), 0.0f);
            float ewy = fmaxf(fmaxf(p2y, g2y) - fminf(p1y, g1y), 0.0f);
            float ediag = ewx*ewx + ewy*ewy;
            float ciou = iou - cd / fmaxf(ediag, 1e-6f);
            float da = atanf(pw / fmaxf(ph, 1e-6f)) - atanf(gw / fmaxf(gh, 1e-6f));
            const float PI2INV4 = 4.0f / (float)(M_PI * M_PI);
            float v = PI2INV4 * da * da;
            float alpha = v / fmaxf(1.0f - iou + v, 1e-6f);
            ciou = ciou - alpha * v;
            accLoc = (1.0f - ciou) * bls;

            // class bit union over all matching targets (scatter-set semantics)
            unsigned b0 = 0, b1 = 0, b2 = 0;
            for (int t = 0; t < TT; t++) {
                if (__float_as_int(sAL[t].y) == n) {
                    int c = sCl[t];
                    if (c < 32) b0 |= 1u << c;
                    else if (c < 64) b1 |= 1u << (c - 32);
                    else b2 |= 1u << (c - 64);
                }
            }
            int slot = atomicAdd(&qcnt, 1);
            q[slot] = make_int4(n, (int)b0, (int)b1, (int)b2);
        }
    }
    __syncthreads();

    // ---- phase 2: cooperative class-BCE, one WAVE per queue entry ----
    const int wid = tid >> 6;
    const int lane = tid & 63;
    const int cnt = qcnt;
    for (int e = wid; e < cnt; e += 4) {
        int4 Q = q[e];
        int qn = Q.x;
        int hw = qn % HW;
        int a  = qn / HW;
        const float* pc = in + ((size_t)b*(AA*(5+CC)) + (size_t)a*(5+CC) + 5)*HW + hw;
        unsigned bits0 = (unsigned)Q.y, bits1 = (unsigned)Q.z, bits2 = (unsigned)Q.w;

        // lane handles class c = lane and c = lane + 64 (lanes 0..15)
        int c0i = lane;
        float lg0 = pc[(size_t)c0i * HW];
        float v0;
        {
            float pp = fminf(fmaxf(sigf(lg0), 1e-7f), 1.0f - 1e-7f);
            unsigned bit = (c0i < 32 ? (bits0 >> c0i) : (bits1 >> (c0i - 32))) & 1u;
            v0 = bit ? -logf(pp) : -logf(1.0f - pp);
        }
        float v1 = 0.0f;
        if (lane < CC - 64) {
            int c1i = lane + 64;
            float lg1 = pc[(size_t)c1i * HW];
            float pp = fminf(fmaxf(sigf(lg1), 1e-7f), 1.0f - 1e-7f);
            unsigned bit = (bits2 >> (c1i - 64)) & 1u;
            v1 = bit ? -logf(pp) : -logf(1.0f - pp);
        }
        float s = v0 + v1;
        for (int off = 32; off > 0; off >>= 1) s += __shfl_down(s, off);
        if (lane == 0) atomicAdd(&sCls, s);
    }

    // ---- block reduction: conf + loc ----
    for (int off = 32; off > 0; off >>= 1) {
        accConf += __shfl_down(accConf, off);
        accLoc  += __shfl_down(accLoc,  off);
    }
    if (lane == 0) { sred[0][wid] = accConf; sred[1][wid] = accLoc; }
    __syncthreads();
    if (tid == 0) {
        float c0 = 0.f, c2 = 0.f;
        #pragma unroll
        for (int w = 0; w < 4; w++) { c0 += sred[0][w]; c2 += sred[1][w]; }
        const int bid = blockIdx.y * CHUNKS + blockIdx.x;
        part[0*NBLK + bid] = c0;    // conf
        part[1*NBLK + bid] = sCls;  // cls
        part[2*NBLK + bid] = c2;    // loc
    }
}

// ---- final reduce: 544 partials x 3 comps -> 4 outputs, one block ----
__global__ __launch_bounds__(256) void yolo_fin(const float* __restrict__ part,
                                                float* __restrict__ out)
{
    __shared__ float sred[3][4];
    float c0 = 0.f, c1 = 0.f, c2 = 0.f;
    for (int k = threadIdx.x; k < NBLK; k += 256) {
        c0 += part[0*NBLK + k];
        c1 += part[1*NBLK + k];
        c2 += part[2*NBLK + k];
    }
    for (int off = 32; off > 0; off >>= 1) {
        c0 += __shfl_down(c0, off);
        c1 += __shfl_down(c1, off);
        c2 += __shfl_down(c2, off);
    }
    int wid = threadIdx.x >> 6;
    int lane = threadIdx.x & 63;
    if (lane == 0) { sred[0][wid] = c0; sred[1][wid] = c1; sred[2][wid] = c2; }
    __syncthreads();
    if (threadIdx.x == 0) {
        float s0 = 0.f, s1 = 0.f, s2 = 0.f;
        #pragma unroll
        for (int w = 0; w < 4; w++) { s0 += sred[0][w]; s1 += sred[1][w]; s2 += sred[2][w]; }
        const float inv_bs = 1.0f / (float)BS;
        s0 *= inv_bs; s1 *= inv_bs; s2 *= inv_bs;
        out[0] = s0 + s1 + s2;
        out[1] = s0;
        out[2] = s1;
        out[3] = s2;
    }
}

extern "C" void kernel_launch(void* const* d_in, const int* in_sizes, int n_in,
                              void* d_out, int out_size, void* d_ws, size_t ws_size,
                              hipStream_t stream) {
    const float* inp = (const float*)d_in[0];          // (8, 255, 76, 76) fp32
    const float* tb  = (const float*)d_in[1];          // (8, 50, 4) fp32
    const int*   tc  = (const int*)d_in[2];            // (8, 50) int32
    float* out = (float*)d_out;                        // 4 fp32 scalars
    float* part = (float*)d_ws;                        // 3*NBLK floats

    yolo_main<<<dim3(CHUNKS, BS), 256, 0, stream>>>(inp, tb, tc, part);
    yolo_fin<<<1, 256, 0, stream>>>(part, out);
}